// Round 6
// baseline (111.155 us; speedup 1.0000x reference)
//
#include <hip/hip_runtime.h>

// out[b,i,j,d] = sum_{k<c} A[b,i,k,d] * B[b,k,j,d]   for i,j < c, else 0
// A: (256,64,64,32) f32, strides: b:131072, i:2048, k:32, d:1
// B: (256,64,64,32) f32, strides: b:131072, k:2048, j:32, d:1
//
// v6: v2's proven scalar inner loop, but 256-thread blocks (4 waves) with
// thread = (d, 8 j's), ICHUNK=4, grid = 16*256 = 4096 in ic*256+b order
// (keeps blockIdx%8 == b%8 -> same-XCD L2 reuse of the B slab).
// Mechanism: ~60 VGPR @ 256 thr -> 8 waves/SIMD resident (2x v2) to hide
// global-load latency; finer items halve the c=64 tail. No sort (v5 showed
// it trades scheduling for +85MB HBM fetch, net zero).

#define BATCH 256
#define NN 64
#define ND 32
#define BSTRIDE (NN * NN * ND)   // 131072
#define RSTRIDE (NN * ND)        // 2048
#define ICHUNK 4
#define NITEMS (BATCH * (NN / ICHUNK))  // 4096

__global__ __launch_bounds__(256, 8) void mp_kernel(
    const float* __restrict__ A,
    const float* __restrict__ B,
    const int* __restrict__ counts,
    float* __restrict__ out)
{
    const int b  = blockIdx.x & (BATCH - 1);
    const int ic = blockIdx.x >> 8;      // 0..15
    const int i0 = ic * ICHUNK;
    const int c  = counts[b];
    const int tid = (int)threadIdx.x;
    const int d  = tid & 31;             // channel
    const int jg = tid >> 5;             // 0..7, group of 8 j's
    const int jb = jg << 3;              // j base

    const size_t base = (size_t)b * BSTRIDE;
    float* __restrict__ Ob = out + base + (size_t)i0 * RSTRIDE + (size_t)jb * ND + d;

    // fast path: whole i-chunk invalid -> zero-fill and retire
    if (i0 >= c) {
        #pragma unroll
        for (int ii = 0; ii < ICHUNK; ++ii)
            #pragma unroll
            for (int jj = 0; jj < 8; ++jj)
                Ob[(size_t)ii * RSTRIDE + jj * ND] = 0.0f;
        return;
    }

    const float* __restrict__ Ai = A + base + (size_t)i0 * RSTRIDE + d;
    const float* __restrict__ Bb = B + base + (size_t)jb * ND + d;

    float acc[ICHUNK][8];
    #pragma unroll
    for (int ii = 0; ii < ICHUNK; ++ii)
        #pragma unroll
        for (int jj = 0; jj < 8; ++jj)
            acc[ii][jj] = 0.0f;

    // wave w (tid>>6) covers j in [16w, 16w+16); skip compute if all invalid
    const bool waveActive = (((tid >> 6) << 4) < c);

    if (waveActive) {
        #pragma unroll 2
        for (int k = 0; k < c; ++k) {
            float av[ICHUNK];
            #pragma unroll
            for (int ii = 0; ii < ICHUNK; ++ii)
                av[ii] = Ai[(size_t)ii * RSTRIDE + k * ND];
            float bv[8];
            #pragma unroll
            for (int jj = 0; jj < 8; ++jj)
                bv[jj] = Bb[(size_t)k * RSTRIDE + jj * ND];
            #pragma unroll
            for (int ii = 0; ii < ICHUNK; ++ii)
                #pragma unroll
                for (int jj = 0; jj < 8; ++jj)
                    acc[ii][jj] = fmaf(av[ii], bv[jj], acc[ii][jj]);
        }
    }

    // masked store (output poisoned before timing -> write everything)
    #pragma unroll
    for (int ii = 0; ii < ICHUNK; ++ii) {
        const bool iv = (i0 + ii) < c;
        #pragma unroll
        for (int jj = 0; jj < 8; ++jj) {
            const bool v = iv && ((jb + jj) < c);
            Ob[(size_t)ii * RSTRIDE + jj * ND] = v ? acc[ii][jj] : 0.0f;
        }
    }
}

extern "C" void kernel_launch(void* const* d_in, const int* in_sizes, int n_in,
                              void* d_out, int out_size, void* d_ws, size_t ws_size,
                              hipStream_t stream)
{
    const float* A      = (const float*)d_in[0];
    const float* B      = (const float*)d_in[1];
    const int*   counts = (const int*)d_in[2];
    float* out = (float*)d_out;

    mp_kernel<<<dim3(NITEMS), dim3(256), 0, stream>>>(A, B, counts, out);
}